// Round 4
// baseline (255.642 us; speedup 1.0000x reference)
//
#include <hip/hip_runtime.h>
#include <math.h>

#define NAGENT 4096
#define TOPK 32
#define CANDCAP 2048

// ---------------------------------------------------------------------------
// Kernel 1: exact top-32 nearest neighbors. VERBATIM from R12 (PASSED).
// ---------------------------------------------------------------------------
__global__ __launch_bounds__(256) void topk_kernel(
    const float* __restrict__ states, int* __restrict__ idx_out)
{
    const int i = blockIdx.x;
    const int t = threadIdx.x;
    const int lane = t & 63;
    __shared__ unsigned int hist[1024];
    __shared__ unsigned int wsum[4];
    __shared__ unsigned long long cand[CANDCAP];
    __shared__ int ccount;
    __shared__ unsigned int cutB;

    #pragma unroll
    for (int u = 0; u < 4; ++u) hist[t + u * 256] = 0u;
    if (t == 0) ccount = 0;

    const float4 si = ((const float4*)states)[i];
    __syncthreads();

    unsigned int mybits[16];
    #pragma unroll
    for (int u = 0; u < 16; ++u) {
        int j = t + u * 256;
        float4 sj = ((const float4*)states)[j];
        float dx = __fsub_rn(si.x, sj.x);
        float dy = __fsub_rn(si.y, sj.y);
        float s  = __fadd_rn(__fadd_rn(__fmul_rn(dx, dx), __fmul_rn(dy, dy)), 1e-4f);
        float dv = sqrtf(s);
        mybits[u] = __float_as_uint(dv);
        unsigned int bin = (unsigned int)(dv * 256.0f);
        if (bin > 1023u) bin = 1023u;
        atomicAdd(&hist[bin], 1u);
    }
    __syncthreads();

    unsigned int h0 = hist[t * 4 + 0], h1 = hist[t * 4 + 1];
    unsigned int h2 = hist[t * 4 + 2], h3 = hist[t * 4 + 3];
    unsigned int v = h0 + h1 + h2 + h3;
    unsigned int inc = v;
    #pragma unroll
    for (int off = 1; off < 64; off <<= 1) {
        unsigned int u = __shfl_up(inc, off, 64);
        if (lane >= off) inc += u;
    }
    if (lane == 63) wsum[t >> 6] = inc;
    __syncthreads();
    unsigned int woff = 0;
    for (int w = 0; w < (t >> 6); ++w) woff += wsum[w];
    unsigned int incl = inc + woff;
    unsigned int exc  = incl - v;
    if (exc < TOPK && incl >= TOPK) {
        unsigned int cum = exc;
        unsigned int hh[4] = {h0, h1, h2, h3};
        int b = t * 4 + 3;
        #pragma unroll
        for (int q = 0; q < 4; ++q) {
            cum += hh[q];
            if (cum >= TOPK) { b = t * 4 + q; break; }
        }
        cutB = (unsigned int)b;
    }
    __syncthreads();

    const unsigned int B = cutB;
    #pragma unroll
    for (int u = 0; u < 16; ++u) {
        float dv = __uint_as_float(mybits[u]);
        unsigned int bin = (unsigned int)(dv * 256.0f);
        if (bin > 1023u) bin = 1023u;
        if (bin <= B) {
            int pos = atomicAdd(&ccount, 1);
            if (pos < CANDCAP)
                cand[pos] = ((unsigned long long)mybits[u] << 32)
                          | (unsigned int)(t + u * 256);
        }
    }
    __syncthreads();

    const int C = (ccount < CANDCAP) ? ccount : CANDCAP;
    for (int q = t; q < C; q += 256) {
        unsigned long long key = cand[q];
        int rank = 0;
        for (int r = 0; r < C; ++r) rank += (cand[r] < key) ? 1 : 0;
        if (rank < TOPK) idx_out[i * TOPK + rank] = (int)(key & 0xffffffffu);
    }
}

// ---------------------------------------------------------------------------
// DPP max helper: VALU-only cross-lane max step (no DS pipe).
// ---------------------------------------------------------------------------
template <int CTRL>
__device__ __forceinline__ float dpp_max_step(float x)
{
    int y = __builtin_amdgcn_update_dpp(0, __float_as_int(x), CTRL, 0xF, 0xF, true);
    return fmaxf(x, __int_as_float(y));
}

// ---------------------------------------------------------------------------
// Kernel 2 (fused) R17 = R16 structure + RAW-RESHAPE FIX. R16 fed lane p's
// own neighbor features to h1 (transpose semantics); the reference does a
// raw reshape [N,K,5]->[N,5,K], so channel f at position p is
// flat[f*32+p] of the [32][5] row-major xk buffer (feature (f*32+p)%5 of
// neighbor (f*32+p)/5). Fix: stage flat[4][160] in LDS exactly as R13
// (lane p writes p*5+f; reads f*32+p, conflict-free both ways), one extra
// barrier. h2 remains ZERO-LDS: h1[64] lane-private VGPRs, W2 rows via
// wave-uniform scalar loads. Argmax: 4 DPP max + shfl_xor(16) + ballot/ffs
// (first-index tie-break == jnp.argmax). Accumulation order bitwise R13.
// ---------------------------------------------------------------------------
__global__ __launch_bounds__(256, 4) void fused_kernel(
    const float* __restrict__ states, const float* __restrict__ goals,
    const float* __restrict__ W1,  const float* __restrict__ b1,
    const float* __restrict__ W2,  const float* __restrict__ b2,
    const float* __restrict__ Wd1, const float* __restrict__ bd1,
    const float* __restrict__ Wd2, const float* __restrict__ bd2,
    const float* __restrict__ Wd3, const float* __restrict__ bd3,
    const float* __restrict__ Wd4, const float* __restrict__ bd4,
    const int* __restrict__ idx_in, float* __restrict__ out)
{
    const int t = threadIdx.x;
    const int w = t >> 6;               // wave 0..3
    const int l = t & 63;
    const int pair  = w >> 1;           // agent pair 0..1
    const int obase = (w & 1) << 6;     // this wave's o-range start (0 or 64)
    const int half  = l >> 5;           // which agent of the pair
    const int fa    = pair * 2 + half;  // local agent 0..3
    const int g     = blockIdx.x * 4 + fa;
    const int p     = l & 31;           // neighbor slot owned by this lane

    __shared__ __attribute__((aligned(16))) float flat[4][160];   // 2.5 KB
    __shared__ __attribute__((aligned(16))) float featb[4][132];  // 2.1 KB
    __shared__ __attribute__((aligned(16))) float zpool[4][264];  // 4.2 KB

    // ---- gather: stage xk row-major [32][5] (both waves of a pair write
    //      identical values -- benign). Mask stays lane-private (raw p).
    int j = idx_in[g * TOPK + p];
    float4 sj = ((const float4*)states)[j];
    float4 si = ((const float4*)states)[g];
    float d0 = si.x - sj.x;
    float d1 = si.y - sj.y;
    float d2 = si.z - sj.z;
    float d3 = si.w - sj.w;
    float slf = (j == g) ? 1.0f : 0.0f;
    float dist = sqrtf(__fadd_rn(__fmul_rn(d0, d0), __fmul_rn(d1, d1)));
    float mask = (dist < 1.0f) ? 1.0f : 0.0f;

    flat[fa][p * 5 + 0] = d0;
    flat[fa][p * 5 + 1] = d1;
    flat[fa][p * 5 + 2] = d2;
    flat[fa][p * 5 + 3] = d3;
    flat[fa][p * 5 + 4] = slf;

    if (p < 4) {
        float2 gi = ((const float2*)goals)[g];
        float v = (p == 0) ? (si.x - gi.x)
                : (p == 1) ? (si.y - gi.y)
                : (p == 2) ? si.z : si.w;
        featb[fa][128 + p] = v;
    }
    __syncthreads();   // flat visible across the pair's two waves

    // ---- raw-reshape inputs for this position p (5 scrambled elements)
    float in5[5];
    #pragma unroll
    for (int f = 0; f < 5; ++f) in5[f] = flat[fa][f * 32 + p];

    // ---- h1: lane-private registers, W1/b1 via wave-uniform scalar loads
    float h1reg[64];
    #pragma unroll
    for (int c = 0; c < 64; ++c) {
        float acc = b1[c];
        #pragma unroll
        for (int f = 0; f < 5; ++f)
            acc += W1[c * 5 + f] * in5[f];     // f ascending: same order as R13
        h1reg[c] = fmaxf(acc, 0.0f);
    }

    // ---- h2 + argmax: o in [obase, obase+64); W2 row streams through SGPRs
    for (int oi = 0; oi < 64; ++oi) {
        const int o = obase + oi;
        const float* __restrict__ w2r = &W2[o * 64];
        float acc = 0.0f;
        #pragma unroll
        for (int c = 0; c < 64; ++c)
            acc += w2r[c] * h1reg[c];          // c ascending: same order as R13
        float val = fmaxf(acc + b2[o], 0.0f) * mask;

        // 32-lane max within agent half: 4 DPP steps (VALU) + 1 xor16 shuffle
        float m = val;
        m = dpp_max_step<0xB1>(m);    // quad_perm [1,0,3,2] : max over 2
        m = dpp_max_step<0x4E>(m);    // quad_perm [2,3,0,1] : max over 4
        m = dpp_max_step<0x141>(m);   // row_half_mirror     : max over 8
        m = dpp_max_step<0x140>(m);   // row_mirror          : max over 16
        m = fmaxf(m, __shfl_xor(m, 16, 64));   // max over 32 (stays in half)

        unsigned long long bal = __ballot(val == m);
        unsigned int bh = half ? (unsigned int)(bal >> 32) : (unsigned int)bal;
        float pb = (float)(__ffs(bh) - 1);     // first max = smallest p (jnp.argmax)
        if (p == 0) featb[fa][o] = pb;
    }

    __syncthreads();   // featb rows complete (both o-halves, goal feats)

    // ---- dense: wave w handles agent blockIdx.x*4 + w (R15 code, verbatim)
    float* z1s = &zpool[w][0];    // 64
    float* z2s = z1s + 64;        // 128
    float* z3s = z1s + 192;       // 64
    float* kvs = z1s + 256;       // 4
    const int gd = blockIdx.x * 4 + w;

    {
        float a0 = bd1[l];
        for (int k = 0; k < 33; ++k) {
            float4 wv = *(const float4*)&Wd1[l * 132 + 4 * k];
            float4 f0 = *(const float4*)&featb[w][4 * k];
            a0 += wv.x * f0.x; a0 += wv.y * f0.y; a0 += wv.z * f0.z; a0 += wv.w * f0.w;
        }
        z1s[l] = fmaxf(a0, 0.0f);
    }

    {
        float accA = bd2[l];
        float accB = bd2[l + 64];
        for (int k = 0; k < 16; ++k) {
            float4 wa = *(const float4*)&Wd2[l * 64 + 4 * k];
            float4 wb = *(const float4*)&Wd2[(l + 64) * 64 + 4 * k];
            float4 f0 = *(const float4*)&z1s[4 * k];
            accA += wa.x * f0.x; accA += wa.y * f0.y;
            accA += wa.z * f0.z; accA += wa.w * f0.w;
            accB += wb.x * f0.x; accB += wb.y * f0.y;
            accB += wb.z * f0.z; accB += wb.w * f0.w;
        }
        z2s[l]      = fmaxf(accA, 0.0f);
        z2s[l + 64] = fmaxf(accB, 0.0f);
    }

    {
        float a0 = bd3[l];
        for (int k = 0; k < 32; ++k) {
            float4 wv = *(const float4*)&Wd3[l * 128 + 4 * k];
            float4 f0 = *(const float4*)&z2s[4 * k];
            a0 += wv.x * f0.x; a0 += wv.y * f0.y; a0 += wv.z * f0.z; a0 += wv.w * f0.w;
        }
        z3s[l] = fmaxf(a0, 0.0f);
    }

    if (l < 4) {
        float acc = bd4[l];
        for (int c = 0; c < 64; ++c) acc += Wd4[l * 64 + c] * z3s[c];
        kvs[l] = 2.0f / (1.0f + expf(-acc)) + 0.2f;
    }
    if (l < 2) {
        float ka = kvs[2 * l + 0];
        float kb = kvs[2 * l + 1];
        float rel = featb[w][128 + l];
        float vel = featb[w][130 + l];
        out[gd * 2 + l] = -(ka * rel + kb * vel);
    }
}

extern "C" void kernel_launch(void* const* d_in, const int* in_sizes, int n_in,
                              void* d_out, int out_size, void* d_ws, size_t ws_size,
                              hipStream_t stream)
{
    const float* states = (const float*)d_in[0];
    const float* goals  = (const float*)d_in[1];
    const float* W1  = (const float*)d_in[2];
    const float* b1  = (const float*)d_in[3];
    const float* W2  = (const float*)d_in[4];
    const float* b2  = (const float*)d_in[5];
    const float* Wd1 = (const float*)d_in[6];
    const float* bd1 = (const float*)d_in[7];
    const float* Wd2 = (const float*)d_in[8];
    const float* bd2 = (const float*)d_in[9];
    const float* Wd3 = (const float*)d_in[10];
    const float* bd3 = (const float*)d_in[11];
    const float* Wd4 = (const float*)d_in[12];
    const float* bd4 = (const float*)d_in[13];

    int*   idx = (int*)d_ws;   // 512 KB
    float* out = (float*)d_out;

    topk_kernel<<<NAGENT, 256, 0, stream>>>(states, idx);
    fused_kernel<<<NAGENT / 4, 256, 0, stream>>>(states, goals, W1, b1, W2, b2,
                                                 Wd1, bd1, Wd2, bd2, Wd3, bd3,
                                                 Wd4, bd4, idx, out);
}